// Round 12
// baseline (349.279 us; speedup 1.0000x reference)
//
#include <hip/hip_runtime.h>
#include <hip/hip_fp16.h>
#include <stdint.h>

#define NN 100000
#define EE 1600000
#define FD 128
#define ELLCAP 64      // max deg <= 64 PROVEN by R6 pass
#define NB 782         // buckets of 128 nodes
#define CHUNK 2048     // R12: was 8192 -> grid 196 (<256 CUs, 12.5% occ); now 782
#define NBLK ((EE + CHUNK - 1) / CHUNK)
#define BCAP 2560
#define OCAP 262144

typedef _Float16 half8 __attribute__((ext_vector_type(8)));
typedef float    floatx4 __attribute__((ext_vector_type(4)));

// ---------------------------------------------------------------------------
// threefry2x32 (JAX partitionable mode, verified R2)
// ---------------------------------------------------------------------------
struct TF2 { uint32_t x0, x1; };

__host__ __device__ constexpr uint32_t rotl32c(uint32_t x, int d) {
  return (x << d) | (x >> (32 - d));
}

__host__ __device__ constexpr TF2 threefry2x32(uint32_t k0, uint32_t k1,
                                               uint32_t c0, uint32_t c1) {
  const uint32_t ks2 = k0 ^ k1 ^ 0x1BD11BDAu;
  uint32_t x0 = c0 + k0;
  uint32_t x1 = c1 + k1;
  const int r0[4] = {13, 15, 26, 6};
  const int r1[4] = {17, 29, 16, 24};
  for (int i = 0; i < 4; i++) { x0 += x1; x1 = rotl32c(x1, r0[i]); x1 ^= x0; }
  x0 += k1;  x1 += ks2 + 1u;
  for (int i = 0; i < 4; i++) { x0 += x1; x1 = rotl32c(x1, r1[i]); x1 ^= x0; }
  x0 += ks2; x1 += k0 + 2u;
  for (int i = 0; i < 4; i++) { x0 += x1; x1 = rotl32c(x1, r0[i]); x1 ^= x0; }
  x0 += k0;  x1 += k1 + 3u;
  for (int i = 0; i < 4; i++) { x0 += x1; x1 = rotl32c(x1, r1[i]); x1 ^= x0; }
  x0 += k1;  x1 += ks2 + 4u;
  for (int i = 0; i < 4; i++) { x0 += x1; x1 = rotl32c(x1, r0[i]); x1 ^= x0; }
  x0 += ks2; x1 += k0 + 5u;
  return TF2{x0, x1};
}

constexpr TF2 DK1 = threefry2x32(0u, 42u, 0u, 0u);
constexpr TF2 DK2 = threefry2x32(0u, 42u, 0u, 1u);

__device__ __forceinline__ float drop_scale(uint32_t k0, uint32_t k1, uint32_t m) {
  TF2 r = threefry2x32(k0, k1, 0u, m);
  const uint32_t bits = r.x0 ^ r.x1;
  float u = __uint_as_float((bits >> 9) | 0x3f800000u) - 1.0f;
  return (u < 0.9f) ? (1.0f / 0.9f) : 0.0f;
}

// ---------------------------------------------------------------------------
// Build phase 1 (R9 structure; R12: CHUNK 2048 for ~3 blocks/CU occupancy —
// at 196 blocks the hist/scan/reorder chain ran at raw latency. Extra global
// tail atomics (~567K vs 153K) accepted: scatter was latency-bound).
// ---------------------------------------------------------------------------
__global__ __launch_bounds__(256) void k_scatter(const int* __restrict__ src,
                                                 const int* __restrict__ dst,
                                                 unsigned* __restrict__ gcnt,
                                                 unsigned* __restrict__ ocnt,
                                                 int* __restrict__ ebuf,
                                                 int2* __restrict__ ovf) {
  __shared__ unsigned sHist[1024];
  __shared__ unsigned sScan[1024];
  __shared__ unsigned sCur[784];
  __shared__ unsigned sPart[256];
  __shared__ int      sPay[CHUNK];
  const int tid  = threadIdx.x;
  const int base = blockIdx.x * CHUNK;

  for (int i = tid; i < 1024; i += 256) sHist[i] = 0u;
  __syncthreads();

#pragma unroll
  for (int j = 0; j < CHUNK / 256; ++j) {
    const int e = base + j * 256 + tid;
    if (e < EE) atomicAdd(&sHist[dst[e] >> 7], 1u);
  }
  __syncthreads();

  {
    const unsigned s0 = sHist[4 * tid + 0];
    const unsigned s1 = sHist[4 * tid + 1];
    const unsigned s2 = sHist[4 * tid + 2];
    const unsigned s3 = sHist[4 * tid + 3];
    sPart[tid] = s0 + s1 + s2 + s3;
    __syncthreads();
    for (int off = 1; off < 256; off <<= 1) {
      unsigned v = 0u;
      if (tid >= off) v = sPart[tid - off];
      __syncthreads();
      if (tid >= off) sPart[tid] += v;
      __syncthreads();
    }
    const unsigned excl = (tid == 0) ? 0u : sPart[tid - 1];
    sScan[4 * tid + 0] = excl;
    sScan[4 * tid + 1] = excl + s0;
    sScan[4 * tid + 2] = excl + s0 + s1;
    sScan[4 * tid + 3] = excl + s0 + s1 + s2;
  }
  for (int i = tid; i < NB; i += 256) sCur[i] = 0u;
  __syncthreads();

#pragma unroll
  for (int j = 0; j < CHUNK / 256; ++j) {
    const int e = base + j * 256 + tid;
    if (e < EE) {
      const int s = src[e];
      const int d = dst[e];
      const int b = d >> 7;
      const unsigned p = sScan[b] + atomicAdd(&sCur[b], 1u);
      sPay[p] = ((d & 127) << 17) | s;
    }
  }
  __syncthreads();

  for (int b = tid; b < NB; b += 256) {
    const unsigned c = sHist[b];
    if (c == 0u) continue;
    const unsigned gb = atomicAdd(&gcnt[b], c);
    const unsigned lo = sScan[b];
    for (unsigned j = 0; j < c; ++j) {
      const unsigned gpos = gb + j;
      const int pay = sPay[lo + j];
      if (gpos < BCAP) {
        ebuf[(size_t)b * BCAP + gpos] = pay;
      } else {
        const unsigned o = atomicAdd(ocnt, 1u);
        if (o < OCAP) ovf[o] = make_int2((b << 7) | ((pay >> 17) & 127),
                                         pay & 0x1FFFF);
      }
    }
  }
}

// ---------------------------------------------------------------------------
// Build phase 2 (unchanged R9)
// ---------------------------------------------------------------------------
__global__ __launch_bounds__(256) void k_build(const unsigned* __restrict__ gcnt,
                                               const unsigned* __restrict__ ocnt,
                                               const int* __restrict__ ebuf,
                                               const int2* __restrict__ ovf,
                                               int* __restrict__ ell,
                                               unsigned* __restrict__ deg,
                                               float* __restrict__ dinv) {
  __shared__ int      sEll[128 * ELLCAP];
  __shared__ unsigned sFill[128];
  const int b   = blockIdx.x;
  const int tid = threadIdx.x;
  if (tid < 128) sFill[tid] = 0u;
  __syncthreads();

  unsigned c = gcnt[b];
  if (c > BCAP) c = BCAP;
  const int* basep = ebuf + (size_t)b * BCAP;
  for (unsigned i = tid; i < c; i += 256) {
    const int p  = basep[i];
    const int dl = (p >> 17) & 127;
    const unsigned sl = atomicAdd(&sFill[dl], 1u);
    if (sl < ELLCAP) sEll[dl * ELLCAP + sl] = p & 0x1FFFF;
  }
  {
    unsigned oc = *ocnt;
    if (oc > OCAP) oc = OCAP;
    for (unsigned i = tid; i < oc; i += 256) {
      const int2 p = ovf[i];
      if ((p.x >> 7) == b) {
        const int dl = p.x & 127;
        const unsigned sl = atomicAdd(&sFill[dl], 1u);
        if (sl < ELLCAP) sEll[dl * ELLCAP + sl] = p.y;
      }
    }
  }
  __syncthreads();

  const int node0 = b * 128;
  const int limRows = (NN - node0) < 128 ? (NN - node0) : 128;
  int4* g = (int4*)(ell + (size_t)node0 * ELLCAP);
  const int4* l = (const int4*)sEll;
  const int limV = limRows * (ELLCAP / 4);
  for (int i = tid; i < limV; i += 256) g[i] = l[i];
  if (tid < 128 && node0 + tid < NN) {
    const unsigned d = sFill[tid];
    deg[node0 + tid] = d;
    dinv[node0 + tid] = 1.0f / sqrtf((float)d + 1.0f);
  }
}

// ---------------------------------------------------------------------------
// GEMM R12: fp16 MFMA, LDS-staged epilogue.
// R11 epilogue did 64 scalar 2-B global stores/thread (12.8M 2-B stores per
// GEMM) — likely 2-3x the memory-floor time. Now: stage C tile into the
// dead sWT LDS (barrier-protected reuse), then 8 coalesced half8 stores per
// thread. Row stride 136 halfs = 272 B (16-B aligned for b128).
// ---------------------------------------------------------------------------
template <typename IN>
__global__ __launch_bounds__(256) void k_gemm(const IN* __restrict__ X,
                                              const float* __restrict__ W,
                                              __half* __restrict__ H) {
  __shared__ _Float16 sWT[128][136];   // 34.8 KB; W^T, later reused as C tile
  const int tid  = threadIdx.x;
  const int wave = tid >> 6;
  const int lane = tid & 63;
  const int quad = lane >> 4;
  const int m    = lane & 15;
  const int row0 = blockIdx.x * 128;

  // stage W^T (one-time)
  {
    const int n = tid & 127, g = tid >> 7;
#pragma unroll 4
    for (int j = 0; j < 32; ++j) {
      const int k = (g * 32 + j) * 2;
      union { _Float16 h[2]; uint32_t u; } p;
      p.h[0] = (_Float16)W[k * 128 + n];
      p.h[1] = (_Float16)W[(k + 1) * 128 + n];
      *(uint32_t*)&sWT[n][k] = p.u;
    }
  }
  __syncthreads();

  floatx4 acc[2][8];
#pragma unroll
  for (int rt = 0; rt < 2; ++rt)
#pragma unroll
    for (int ct = 0; ct < 8; ++ct) acc[rt][ct] = (floatx4){0.f, 0.f, 0.f, 0.f};

#pragma unroll
  for (int kk = 0; kk < 4; ++kk) {
    const int kb = kk * 32 + quad * 8;
    half8 a[2];
#pragma unroll
    for (int rt = 0; rt < 2; ++rt) {
      int gr = row0 + wave * 32 + rt * 16 + m;
      if (gr >= NN) gr = NN - 1;               // clamp (stores guarded)
      if constexpr (sizeof(IN) == 4) {
        const float4 lo = *(const float4*)(X + (size_t)gr * 128 + kb);
        const float4 hi = *(const float4*)(X + (size_t)gr * 128 + kb + 4);
        a[rt][0] = (_Float16)lo.x; a[rt][1] = (_Float16)lo.y;
        a[rt][2] = (_Float16)lo.z; a[rt][3] = (_Float16)lo.w;
        a[rt][4] = (_Float16)hi.x; a[rt][5] = (_Float16)hi.y;
        a[rt][6] = (_Float16)hi.z; a[rt][7] = (_Float16)hi.w;
      } else {
        a[rt] = *(const half8*)(X + (size_t)gr * 128 + kb);   // 16 B
      }
    }
#pragma unroll
    for (int ct = 0; ct < 8; ++ct) {
      const half8 b = *(const half8*)&sWT[ct * 16 + m][kb];
      acc[0][ct] = __builtin_amdgcn_mfma_f32_16x16x32_f16(a[0], b, acc[0][ct], 0, 0, 0);
      acc[1][ct] = __builtin_amdgcn_mfma_f32_16x16x32_f16(a[1], b, acc[1][ct], 0, 0, 0);
    }
  }

  // epilogue: all waves done with sWT -> reuse as C tile
  __syncthreads();
#pragma unroll
  for (int rt = 0; rt < 2; ++rt)
#pragma unroll
    for (int reg = 0; reg < 4; ++reg) {
      const int row = wave * 32 + rt * 16 + quad * 4 + reg;
#pragma unroll
      for (int ct = 0; ct < 8; ++ct)
        sWT[row][ct * 16 + m] = (_Float16)acc[rt][ct][reg];
    }
  __syncthreads();
#pragma unroll
  for (int c = 0; c < 8; ++c) {
    const int chunk = tid + c * 256;     // 0..2047 = 128 rows x 16 segs
    const int row = chunk >> 4;
    const int seg = chunk & 15;
    const int gr = row0 + row;
    if (gr < NN)
      *(half8*)(H + (size_t)gr * 128 + seg * 8) =
          *(const half8*)&sWT[row][seg * 8];
  }
}

// ---------------------------------------------------------------------------
// Aggregation (unchanged R9/R11: fp16 gathers, one node/wave-64, ELL,
// 4-edge unroll; ~1.25x above per-XCD replication floor — near ceiling).
// ---------------------------------------------------------------------------
template <int LAYER>
__global__ __launch_bounds__(256) void k_agg(const __half* __restrict__ H,
                                             const int* __restrict__ ell,
                                             const unsigned* __restrict__ degc,
                                             const float* __restrict__ dinv,
                                             const float* __restrict__ bias,
                                             const float* __restrict__ Wl,
                                             const float* __restrict__ bl,
                                             void* __restrict__ outv) {
  const int tid  = threadIdx.x;
  const int lane = tid & 63;
  const int n    = blockIdx.x * 4 + (tid >> 6);

  const float di = dinv[n];
  const __half2* __restrict__ H2 = (const __half2*)H;

  const float2 hv = __half22float2(H2[(size_t)n * 64 + lane]);
  const float sw = di * di;
  float a0 = hv.x * sw, a1 = hv.y * sw;

  unsigned cnt = degc[n];
  if (cnt > ELLCAP) cnt = ELLCAP;
  const size_t s = (size_t)n * ELLCAP;

  {
    const int m = (int)cnt;
    int srcl = 0; float dl = 0.0f;
    if (lane < m) { srcl = ell[s + lane]; dl = dinv[srcl]; }
    int i = 0;
    for (; i + 4 <= m; i += 4) {
      const int s0 = __shfl(srcl, i + 0, 64);
      const int s1 = __shfl(srcl, i + 1, 64);
      const int s2 = __shfl(srcl, i + 2, 64);
      const int s3 = __shfl(srcl, i + 3, 64);
      const float w0 = __shfl(dl, i + 0, 64) * di;
      const float w1 = __shfl(dl, i + 1, 64) * di;
      const float w2 = __shfl(dl, i + 2, 64) * di;
      const float w3 = __shfl(dl, i + 3, 64) * di;
      const float2 g0 = __half22float2(H2[(size_t)s0 * 64 + lane]);
      const float2 g1 = __half22float2(H2[(size_t)s1 * 64 + lane]);
      const float2 g2 = __half22float2(H2[(size_t)s2 * 64 + lane]);
      const float2 g3 = __half22float2(H2[(size_t)s3 * 64 + lane]);
      a0 = fmaf(w0, g0.x, a0); a1 = fmaf(w0, g0.y, a1);
      a0 = fmaf(w1, g1.x, a0); a1 = fmaf(w1, g1.y, a1);
      a0 = fmaf(w2, g2.x, a0); a1 = fmaf(w2, g2.y, a1);
      a0 = fmaf(w3, g3.x, a0); a1 = fmaf(w3, g3.y, a1);
    }
    for (; i < m; i++) {
      const int src   = __shfl(srcl, i, 64);
      const float wgt = __shfl(dl, i, 64) * di;
      const float2 g  = __half22float2(H2[(size_t)src * 64 + lane]);
      a0 = fmaf(wgt, g.x, a0); a1 = fmaf(wgt, g.y, a1);
    }
  }

  const float2 b = ((const float2*)bias)[lane];
  float v0 = a0 + b.x, v1 = a1 + b.y;
  v0 = v0 >= 0.f ? v0 : 0.01f * v0;
  v1 = v1 >= 0.f ? v1 : 0.01f * v1;

  const uint32_t k0 = (LAYER == 1) ? DK1.x0 : DK2.x0;
  const uint32_t k1 = (LAYER == 1) ? DK1.x1 : DK2.x1;
  const uint32_t mb = (uint32_t)n * 128u + (uint32_t)lane * 2u;
  v0 *= drop_scale(k0, k1, mb + 0u);
  v1 *= drop_scale(k0, k1, mb + 1u);

  if constexpr (LAYER == 1) {
    __half2* out = (__half2*)outv;                      // y1 fp16
    out[(size_t)n * 64 + lane] = __floats2half2_rn(v0, v1);
  } else {
    float* out = (float*)outv;
    const float2 wl = ((const float2*)Wl)[lane];
    float p = v0 * wl.x + v1 * wl.y;
#pragma unroll
    for (int d = 32; d > 0; d >>= 1) p += __shfl_down(p, d, 64);
    if (lane == 0) out[n] = p + bl[0];
  }
}

// ---------------------------------------------------------------------------
extern "C" void kernel_launch(void* const* d_in, const int* in_sizes, int n_in,
                              void* d_out, int out_size, void* d_ws, size_t ws_size,
                              hipStream_t stream) {
  const float* x  = (const float*)d_in[0];
  const int*   ei = (const int*)d_in[1];
  const float* W1 = (const float*)d_in[2];
  const float* b1 = (const float*)d_in[3];
  const float* W2 = (const float*)d_in[4];
  const float* b2 = (const float*)d_in[5];
  const float* Wl = (const float*)d_in[6];
  const float* bl = (const float*)d_in[7];
  float* out = (float*)d_out;

  // workspace (~78 MB): ebuf(8 MB)+ovf(2 MB) ALIAS bufB (dead until agg1)
  unsigned* gcnt = (unsigned*)d_ws;                        // 1024 u32
  unsigned* ocnt = gcnt + 1024;                            // 8 u32
  unsigned* deg  = ocnt + 8;                               // NN u32
  float*    dinv = (float*)(deg + NN);                     // NN f32
  int*      ell  = (int*)(dinv + NN);                      // NN*64 (25.6 MB)
  __half*   bufA = (__half*)(ell + (size_t)NN * ELLCAP);   // NN*128 fp16
  __half*   bufB = bufA + (size_t)NN * FD;                 // NN*128 fp16 (y1)
  int*      ebuf = (int*)bufB;                             // NB*BCAP (8 MB)
  int2*     ovf  = (int2*)(ebuf + (size_t)NB * BCAP);      // 2 MB

  const int* srcI = ei;
  const int* dstI = ei + EE;

  hipMemsetAsync(gcnt, 0, (1024 + 8) * sizeof(unsigned), stream);

  k_scatter<<<NBLK, 256, 0, stream>>>(srcI, dstI, gcnt, ocnt, ebuf, ovf);
  k_build  <<<NB, 256, 0, stream>>>(gcnt, ocnt, ebuf, ovf, ell, deg, dinv);

  const int gemmGrid = (NN + 127) / 128;   // 782
  k_gemm<float> <<<gemmGrid, 256, 0, stream>>>(x, W1, bufA);         // h1 fp16
  k_agg<1><<<NN / 4, 256, 0, stream>>>(bufA, ell, deg, dinv,
                                       b1, nullptr, nullptr, bufB);  // y1 fp16
  k_gemm<__half><<<gemmGrid, 256, 0, stream>>>(bufB, W2, bufA);      // h2 fp16
  k_agg<2><<<NN / 4, 256, 0, stream>>>(bufA, ell, deg, dinv,
                                       b2, Wl, bl, out);             // out
}

// Round 13
// 325.905 us; speedup vs baseline: 1.0717x; 1.0717x over previous
//
#include <hip/hip_runtime.h>
#include <hip/hip_fp16.h>
#include <stdint.h>

#define NN 100000
#define EE 1600000
#define FD 128
#define ELLCAP 64      // max deg <= 64 PROVEN by R6 pass
#define NB 782         // buckets of 128 nodes
#define CHUNK 8192     // R13: back to 8192 (long runs/few tail atomics); occupancy
#define NBLK 196       //      now comes from co-resident gemm blocks in k_g1s
#define BCAP 2560
#define OCAP 262144
#define SMEM_BYTES 45120   // scatter layout (superset of gemm's 34816)

typedef _Float16 half8 __attribute__((ext_vector_type(8)));
typedef float    floatx4 __attribute__((ext_vector_type(4)));

// ---------------------------------------------------------------------------
// threefry2x32 (JAX partitionable mode, verified R2)
// ---------------------------------------------------------------------------
struct TF2 { uint32_t x0, x1; };

__host__ __device__ constexpr uint32_t rotl32c(uint32_t x, int d) {
  return (x << d) | (x >> (32 - d));
}

__host__ __device__ constexpr TF2 threefry2x32(uint32_t k0, uint32_t k1,
                                               uint32_t c0, uint32_t c1) {
  const uint32_t ks2 = k0 ^ k1 ^ 0x1BD11BDAu;
  uint32_t x0 = c0 + k0;
  uint32_t x1 = c1 + k1;
  const int r0[4] = {13, 15, 26, 6};
  const int r1[4] = {17, 29, 16, 24};
  for (int i = 0; i < 4; i++) { x0 += x1; x1 = rotl32c(x1, r0[i]); x1 ^= x0; }
  x0 += k1;  x1 += ks2 + 1u;
  for (int i = 0; i < 4; i++) { x0 += x1; x1 = rotl32c(x1, r1[i]); x1 ^= x0; }
  x0 += ks2; x1 += k0 + 2u;
  for (int i = 0; i < 4; i++) { x0 += x1; x1 = rotl32c(x1, r0[i]); x1 ^= x0; }
  x0 += k0;  x1 += k1 + 3u;
  for (int i = 0; i < 4; i++) { x0 += x1; x1 = rotl32c(x1, r1[i]); x1 ^= x0; }
  x0 += k1;  x1 += ks2 + 4u;
  for (int i = 0; i < 4; i++) { x0 += x1; x1 = rotl32c(x1, r0[i]); x1 ^= x0; }
  x0 += ks2; x1 += k0 + 5u;
  return TF2{x0, x1};
}

constexpr TF2 DK1 = threefry2x32(0u, 42u, 0u, 0u);
constexpr TF2 DK2 = threefry2x32(0u, 42u, 0u, 1u);

__device__ __forceinline__ float drop_scale(uint32_t k0, uint32_t k1, uint32_t m) {
  TF2 r = threefry2x32(k0, k1, 0u, m);
  const uint32_t bits = r.x0 ^ r.x1;
  float u = __uint_as_float((bits >> 9) | 0x3f800000u) - 1.0f;
  return (u < 0.9f) ? (1.0f / 0.9f) : 0.0f;
}

// ---------------------------------------------------------------------------
// Scatter body (R9 logic, CHUNK 8192), on caller-provided LDS.
// ---------------------------------------------------------------------------
__device__ __forceinline__ void scatter_body(char* smem, int bid,
                                             const int* __restrict__ src,
                                             const int* __restrict__ dst,
                                             unsigned* __restrict__ gcnt,
                                             unsigned* __restrict__ ocnt,
                                             int* __restrict__ ebuf,
                                             int2* __restrict__ ovf) {
  unsigned* sHist = (unsigned*)smem;          // [1024]
  unsigned* sScan = sHist + 1024;             // [1024]
  unsigned* sCur  = sScan + 1024;             // [784]
  unsigned* sPart = sCur + 784;               // [256]
  int*      sPay  = (int*)(sPart + 256);      // [8192]
  const int tid  = threadIdx.x;
  const int base = bid * CHUNK;

  for (int i = tid; i < 1024; i += 256) sHist[i] = 0u;
  __syncthreads();

#pragma unroll
  for (int j = 0; j < CHUNK / 256; ++j) {
    const int e = base + j * 256 + tid;
    if (e < EE) atomicAdd(&sHist[dst[e] >> 7], 1u);
  }
  __syncthreads();

  {
    const unsigned s0 = sHist[4 * tid + 0];
    const unsigned s1 = sHist[4 * tid + 1];
    const unsigned s2 = sHist[4 * tid + 2];
    const unsigned s3 = sHist[4 * tid + 3];
    sPart[tid] = s0 + s1 + s2 + s3;
    __syncthreads();
    for (int off = 1; off < 256; off <<= 1) {
      unsigned v = 0u;
      if (tid >= off) v = sPart[tid - off];
      __syncthreads();
      if (tid >= off) sPart[tid] += v;
      __syncthreads();
    }
    const unsigned excl = (tid == 0) ? 0u : sPart[tid - 1];
    sScan[4 * tid + 0] = excl;
    sScan[4 * tid + 1] = excl + s0;
    sScan[4 * tid + 2] = excl + s0 + s1;
    sScan[4 * tid + 3] = excl + s0 + s1 + s2;
  }
  for (int i = tid; i < NB; i += 256) sCur[i] = 0u;
  __syncthreads();

#pragma unroll
  for (int j = 0; j < CHUNK / 256; ++j) {
    const int e = base + j * 256 + tid;
    if (e < EE) {
      const int s = src[e];
      const int d = dst[e];
      const int b = d >> 7;
      const unsigned p = sScan[b] + atomicAdd(&sCur[b], 1u);
      sPay[p] = ((d & 127) << 17) | s;
    }
  }
  __syncthreads();

  for (int b = tid; b < NB; b += 256) {
    const unsigned c = sHist[b];
    if (c == 0u) continue;
    const unsigned gb = atomicAdd(&gcnt[b], c);
    const unsigned lo = sScan[b];
    for (unsigned j = 0; j < c; ++j) {
      const unsigned gpos = gb + j;
      const int pay = sPay[lo + j];
      if (gpos < BCAP) {
        ebuf[(size_t)b * BCAP + gpos] = pay;
      } else {
        const unsigned o = atomicAdd(ocnt, 1u);
        if (o < OCAP) ovf[o] = make_int2((b << 7) | ((pay >> 17) & 127),
                                         pay & 0x1FFFF);
      }
    }
  }
}

// ---------------------------------------------------------------------------
// GEMM body (R12 MFMA kernel as a device function on caller LDS).
// ---------------------------------------------------------------------------
template <typename IN>
__device__ __forceinline__ void gemm_body(char* smem, int bid,
                                          const IN* __restrict__ X,
                                          const float* __restrict__ W,
                                          __half* __restrict__ H) {
  _Float16 (*sWT)[136] = (_Float16(*)[136])smem;   // 34816 B
  const int tid  = threadIdx.x;
  const int wave = tid >> 6;
  const int lane = tid & 63;
  const int quad = lane >> 4;
  const int m    = lane & 15;
  const int row0 = bid * 128;

  {
    const int n = tid & 127, g = tid >> 7;
#pragma unroll 4
    for (int j = 0; j < 32; ++j) {
      const int k = (g * 32 + j) * 2;
      union { _Float16 h[2]; uint32_t u; } p;
      p.h[0] = (_Float16)W[k * 128 + n];
      p.h[1] = (_Float16)W[(k + 1) * 128 + n];
      *(uint32_t*)&sWT[n][k] = p.u;
    }
  }
  __syncthreads();

  floatx4 acc[2][8];
#pragma unroll
  for (int rt = 0; rt < 2; ++rt)
#pragma unroll
    for (int ct = 0; ct < 8; ++ct) acc[rt][ct] = (floatx4){0.f, 0.f, 0.f, 0.f};

#pragma unroll
  for (int kk = 0; kk < 4; ++kk) {
    const int kb = kk * 32 + quad * 8;
    half8 a[2];
#pragma unroll
    for (int rt = 0; rt < 2; ++rt) {
      int gr = row0 + wave * 32 + rt * 16 + m;
      if (gr >= NN) gr = NN - 1;
      if constexpr (sizeof(IN) == 4) {
        const float4 lo = *(const float4*)(X + (size_t)gr * 128 + kb);
        const float4 hi = *(const float4*)(X + (size_t)gr * 128 + kb + 4);
        a[rt][0] = (_Float16)lo.x; a[rt][1] = (_Float16)lo.y;
        a[rt][2] = (_Float16)lo.z; a[rt][3] = (_Float16)lo.w;
        a[rt][4] = (_Float16)hi.x; a[rt][5] = (_Float16)hi.y;
        a[rt][6] = (_Float16)hi.z; a[rt][7] = (_Float16)hi.w;
      } else {
        a[rt] = *(const half8*)(X + (size_t)gr * 128 + kb);
      }
    }
#pragma unroll
    for (int ct = 0; ct < 8; ++ct) {
      const half8 b = *(const half8*)&sWT[ct * 16 + m][kb];
      acc[0][ct] = __builtin_amdgcn_mfma_f32_16x16x32_f16(a[0], b, acc[0][ct], 0, 0, 0);
      acc[1][ct] = __builtin_amdgcn_mfma_f32_16x16x32_f16(a[1], b, acc[1][ct], 0, 0, 0);
    }
  }

  __syncthreads();
#pragma unroll
  for (int rt = 0; rt < 2; ++rt)
#pragma unroll
    for (int reg = 0; reg < 4; ++reg) {
      const int row = wave * 32 + rt * 16 + quad * 4 + reg;
#pragma unroll
      for (int ct = 0; ct < 8; ++ct)
        sWT[row][ct * 16 + m] = (_Float16)acc[rt][ct][reg];
    }
  __syncthreads();
#pragma unroll
  for (int c = 0; c < 8; ++c) {
    const int chunk = tid + c * 256;
    const int row = chunk >> 4;
    const int seg = chunk & 15;
    const int gr = row0 + row;
    if (gr < NN)
      *(half8*)(H + (size_t)gr * 128 + seg * 8) =
          *(const half8*)&sWT[row][seg * 8];
  }
}

// ---------------------------------------------------------------------------
// R13 fused kernel: gemm1 (x@W1) and edge scatter are DATA-INDEPENDENT but
// serialized by the single stream; fusing via block-range split is the only
// overlap mechanism under graph capture. Scatter blocks first (long pole).
// LDS: manual union, 44.1 KB -> 3 blocks/CU.
// ---------------------------------------------------------------------------
__global__ __launch_bounds__(256) void k_g1s(const float* __restrict__ X,
                                             const float* __restrict__ W,
                                             __half* __restrict__ H,
                                             const int* __restrict__ src,
                                             const int* __restrict__ dst,
                                             unsigned* __restrict__ gcnt,
                                             unsigned* __restrict__ ocnt,
                                             int* __restrict__ ebuf,
                                             int2* __restrict__ ovf) {
  __shared__ __align__(16) char smem[SMEM_BYTES];
  if (blockIdx.x < NBLK) {
    scatter_body(smem, blockIdx.x, src, dst, gcnt, ocnt, ebuf, ovf);
  } else {
    gemm_body<float>(smem, blockIdx.x - NBLK, X, W, H);
  }
}

// gemm2 standalone (same body)
__global__ __launch_bounds__(256) void k_gemm2(const __half* __restrict__ X,
                                               const float* __restrict__ W,
                                               __half* __restrict__ H) {
  __shared__ __align__(16) char smem[34816];
  gemm_body<__half>(smem, blockIdx.x, X, W, H);
}

// ---------------------------------------------------------------------------
// Build phase 2 (unchanged R9)
// ---------------------------------------------------------------------------
__global__ __launch_bounds__(256) void k_build(const unsigned* __restrict__ gcnt,
                                               const unsigned* __restrict__ ocnt,
                                               const int* __restrict__ ebuf,
                                               const int2* __restrict__ ovf,
                                               int* __restrict__ ell,
                                               unsigned* __restrict__ deg,
                                               float* __restrict__ dinv) {
  __shared__ int      sEll[128 * ELLCAP];
  __shared__ unsigned sFill[128];
  const int b   = blockIdx.x;
  const int tid = threadIdx.x;
  if (tid < 128) sFill[tid] = 0u;
  __syncthreads();

  unsigned c = gcnt[b];
  if (c > BCAP) c = BCAP;
  const int* basep = ebuf + (size_t)b * BCAP;
  for (unsigned i = tid; i < c; i += 256) {
    const int p  = basep[i];
    const int dl = (p >> 17) & 127;
    const unsigned sl = atomicAdd(&sFill[dl], 1u);
    if (sl < ELLCAP) sEll[dl * ELLCAP + sl] = p & 0x1FFFF;
  }
  {
    unsigned oc = *ocnt;
    if (oc > OCAP) oc = OCAP;
    for (unsigned i = tid; i < oc; i += 256) {
      const int2 p = ovf[i];
      if ((p.x >> 7) == b) {
        const int dl = p.x & 127;
        const unsigned sl = atomicAdd(&sFill[dl], 1u);
        if (sl < ELLCAP) sEll[dl * ELLCAP + sl] = p.y;
      }
    }
  }
  __syncthreads();

  const int node0 = b * 128;
  const int limRows = (NN - node0) < 128 ? (NN - node0) : 128;
  int4* g = (int4*)(ell + (size_t)node0 * ELLCAP);
  const int4* l = (const int4*)sEll;
  const int limV = limRows * (ELLCAP / 4);
  for (int i = tid; i < limV; i += 256) g[i] = l[i];
  if (tid < 128 && node0 + tid < NN) {
    const unsigned d = sFill[tid];
    deg[node0 + tid] = d;
    dinv[node0 + tid] = 1.0f / sqrtf((float)d + 1.0f);
  }
}

// ---------------------------------------------------------------------------
// Aggregation (unchanged R9/R11; near the per-XCD replication ceiling)
// ---------------------------------------------------------------------------
template <int LAYER>
__global__ __launch_bounds__(256) void k_agg(const __half* __restrict__ H,
                                             const int* __restrict__ ell,
                                             const unsigned* __restrict__ degc,
                                             const float* __restrict__ dinv,
                                             const float* __restrict__ bias,
                                             const float* __restrict__ Wl,
                                             const float* __restrict__ bl,
                                             void* __restrict__ outv) {
  const int tid  = threadIdx.x;
  const int lane = tid & 63;
  const int n    = blockIdx.x * 4 + (tid >> 6);

  const float di = dinv[n];
  const __half2* __restrict__ H2 = (const __half2*)H;

  const float2 hv = __half22float2(H2[(size_t)n * 64 + lane]);
  const float sw = di * di;
  float a0 = hv.x * sw, a1 = hv.y * sw;

  unsigned cnt = degc[n];
  if (cnt > ELLCAP) cnt = ELLCAP;
  const size_t s = (size_t)n * ELLCAP;

  {
    const int m = (int)cnt;
    int srcl = 0; float dl = 0.0f;
    if (lane < m) { srcl = ell[s + lane]; dl = dinv[srcl]; }
    int i = 0;
    for (; i + 4 <= m; i += 4) {
      const int s0 = __shfl(srcl, i + 0, 64);
      const int s1 = __shfl(srcl, i + 1, 64);
      const int s2 = __shfl(srcl, i + 2, 64);
      const int s3 = __shfl(srcl, i + 3, 64);
      const float w0 = __shfl(dl, i + 0, 64) * di;
      const float w1 = __shfl(dl, i + 1, 64) * di;
      const float w2 = __shfl(dl, i + 2, 64) * di;
      const float w3 = __shfl(dl, i + 3, 64) * di;
      const float2 g0 = __half22float2(H2[(size_t)s0 * 64 + lane]);
      const float2 g1 = __half22float2(H2[(size_t)s1 * 64 + lane]);
      const float2 g2 = __half22float2(H2[(size_t)s2 * 64 + lane]);
      const float2 g3 = __half22float2(H2[(size_t)s3 * 64 + lane]);
      a0 = fmaf(w0, g0.x, a0); a1 = fmaf(w0, g0.y, a1);
      a0 = fmaf(w1, g1.x, a0); a1 = fmaf(w1, g1.y, a1);
      a0 = fmaf(w2, g2.x, a0); a1 = fmaf(w2, g2.y, a1);
      a0 = fmaf(w3, g3.x, a0); a1 = fmaf(w3, g3.y, a1);
    }
    for (; i < m; i++) {
      const int src   = __shfl(srcl, i, 64);
      const float wgt = __shfl(dl, i, 64) * di;
      const float2 g  = __half22float2(H2[(size_t)src * 64 + lane]);
      a0 = fmaf(wgt, g.x, a0); a1 = fmaf(wgt, g.y, a1);
    }
  }

  const float2 b = ((const float2*)bias)[lane];
  float v0 = a0 + b.x, v1 = a1 + b.y;
  v0 = v0 >= 0.f ? v0 : 0.01f * v0;
  v1 = v1 >= 0.f ? v1 : 0.01f * v1;

  const uint32_t k0 = (LAYER == 1) ? DK1.x0 : DK2.x0;
  const uint32_t k1 = (LAYER == 1) ? DK1.x1 : DK2.x1;
  const uint32_t mb = (uint32_t)n * 128u + (uint32_t)lane * 2u;
  v0 *= drop_scale(k0, k1, mb + 0u);
  v1 *= drop_scale(k0, k1, mb + 1u);

  if constexpr (LAYER == 1) {
    __half2* out = (__half2*)outv;
    out[(size_t)n * 64 + lane] = __floats2half2_rn(v0, v1);
  } else {
    float* out = (float*)outv;
    const float2 wl = ((const float2*)Wl)[lane];
    float p = v0 * wl.x + v1 * wl.y;
#pragma unroll
    for (int d = 32; d > 0; d >>= 1) p += __shfl_down(p, d, 64);
    if (lane == 0) out[n] = p + bl[0];
  }
}

// ---------------------------------------------------------------------------
extern "C" void kernel_launch(void* const* d_in, const int* in_sizes, int n_in,
                              void* d_out, int out_size, void* d_ws, size_t ws_size,
                              hipStream_t stream) {
  const float* x  = (const float*)d_in[0];
  const int*   ei = (const int*)d_in[1];
  const float* W1 = (const float*)d_in[2];
  const float* b1 = (const float*)d_in[3];
  const float* W2 = (const float*)d_in[4];
  const float* b2 = (const float*)d_in[5];
  const float* Wl = (const float*)d_in[6];
  const float* bl = (const float*)d_in[7];
  float* out = (float*)d_out;

  // workspace (~78 MB): ebuf(8 MB)+ovf(2 MB) ALIAS bufB (dead until agg1)
  unsigned* gcnt = (unsigned*)d_ws;                        // 1024 u32
  unsigned* ocnt = gcnt + 1024;                            // 8 u32
  unsigned* deg  = ocnt + 8;                               // NN u32
  float*    dinv = (float*)(deg + NN);                     // NN f32
  int*      ell  = (int*)(dinv + NN);                      // NN*64 (25.6 MB)
  __half*   bufA = (__half*)(ell + (size_t)NN * ELLCAP);   // NN*128 fp16
  __half*   bufB = bufA + (size_t)NN * FD;                 // NN*128 fp16 (y1)
  int*      ebuf = (int*)bufB;                             // NB*BCAP (8 MB)
  int2*     ovf  = (int2*)(ebuf + (size_t)NB * BCAP);      // 2 MB

  const int* srcI = ei;
  const int* dstI = ei + EE;

  hipMemsetAsync(gcnt, 0, (1024 + 8) * sizeof(unsigned), stream);

  const int gemmGrid = (NN + 127) / 128;   // 782
  k_g1s<<<NBLK + gemmGrid, 256, 0, stream>>>(x, W1, bufA, srcI, dstI,
                                             gcnt, ocnt, ebuf, ovf);
  k_build<<<NB, 256, 0, stream>>>(gcnt, ocnt, ebuf, ovf, ell, deg, dinv);
  k_agg<1><<<NN / 4, 256, 0, stream>>>(bufA, ell, deg, dinv,
                                       b1, nullptr, nullptr, bufB);  // y1 fp16
  k_gemm2<<<gemmGrid, 256, 0, stream>>>(bufB, W2, bufA);             // h2 fp16
  k_agg<2><<<NN / 4, 256, 0, stream>>>(bufA, ell, deg, dinv,
                                       b2, Wl, bl, out);             // out
}

// Round 14
// 302.807 us; speedup vs baseline: 1.1535x; 1.0763x over previous
//
#include <hip/hip_runtime.h>
#include <hip/hip_fp16.h>
#include <stdint.h>

#define NN 100000
#define EE 1600000
#define FD 128
#define ELLCAP 64      // max deg <= 64 PROVEN by R6 pass
#define NB 782         // buckets of 128 nodes
#define CHUNK 8192
#define NBLK 196       // ceil(EE/CHUNK); last block covers 2560 edges
#define SMEM_BYTES 45120   // scatter layout (superset of gemm's 34816)

typedef _Float16 half8 __attribute__((ext_vector_type(8)));
typedef float    floatx4 __attribute__((ext_vector_type(4)));

// ---------------------------------------------------------------------------
// threefry2x32 (JAX partitionable mode, verified R2)
// ---------------------------------------------------------------------------
struct TF2 { uint32_t x0, x1; };

__host__ __device__ constexpr uint32_t rotl32c(uint32_t x, int d) {
  return (x << d) | (x >> (32 - d));
}

__host__ __device__ constexpr TF2 threefry2x32(uint32_t k0, uint32_t k1,
                                               uint32_t c0, uint32_t c1) {
  const uint32_t ks2 = k0 ^ k1 ^ 0x1BD11BDAu;
  uint32_t x0 = c0 + k0;
  uint32_t x1 = c1 + k1;
  const int r0[4] = {13, 15, 26, 6};
  const int r1[4] = {17, 29, 16, 24};
  for (int i = 0; i < 4; i++) { x0 += x1; x1 = rotl32c(x1, r0[i]); x1 ^= x0; }
  x0 += k1;  x1 += ks2 + 1u;
  for (int i = 0; i < 4; i++) { x0 += x1; x1 = rotl32c(x1, r1[i]); x1 ^= x0; }
  x0 += ks2; x1 += k0 + 2u;
  for (int i = 0; i < 4; i++) { x0 += x1; x1 = rotl32c(x1, r0[i]); x1 ^= x0; }
  x0 += k0;  x1 += k1 + 3u;
  for (int i = 0; i < 4; i++) { x0 += x1; x1 = rotl32c(x1, r1[i]); x1 ^= x0; }
  x0 += k1;  x1 += ks2 + 4u;
  for (int i = 0; i < 4; i++) { x0 += x1; x1 = rotl32c(x1, r0[i]); x1 ^= x0; }
  x0 += ks2; x1 += k0 + 5u;
  return TF2{x0, x1};
}

constexpr TF2 DK1 = threefry2x32(0u, 42u, 0u, 0u);
constexpr TF2 DK2 = threefry2x32(0u, 42u, 0u, 1u);

__device__ __forceinline__ float drop_scale(uint32_t k0, uint32_t k1, uint32_t m) {
  TF2 r = threefry2x32(k0, k1, 0u, m);
  const uint32_t bits = r.x0 ^ r.x1;
  float u = __uint_as_float((bits >> 9) | 0x3f800000u) - 1.0f;
  return (u < 0.9f) ? (1.0f / 0.9f) : 0.0f;
}

// ---------------------------------------------------------------------------
// Scatter body R14: DETERMINISTIC block-owned layout — ZERO global atomics.
// R13 flush used ~153K memory-side reservation atomics (~32 B each, R8's
// proven cost) + latency-serial store runs. Now: LDS hist -> scan -> reorder
// (unchanged), then (1) coalesced int4 dump of the whole 8192-payload array
// at ebuf[bid*CHUNK], (2) packed table tcnt[bid][b] = scan<<14 | cnt.
// No overflow path needed: capacity is exact by construction. No memset.
// ---------------------------------------------------------------------------
__device__ __forceinline__ void scatter_body(char* smem, int bid,
                                             const int* __restrict__ src,
                                             const int* __restrict__ dst,
                                             int* __restrict__ ebuf,
                                             unsigned* __restrict__ tcnt) {
  unsigned* sHist = (unsigned*)smem;          // [1024]
  unsigned* sScan = sHist + 1024;             // [1024]
  unsigned* sCur  = sScan + 1024;             // [784]
  unsigned* sPart = sCur + 784;               // [256]
  int*      sPay  = (int*)(sPart + 256);      // [8192]
  const int tid  = threadIdx.x;
  const int base = bid * CHUNK;

  for (int i = tid; i < 1024; i += 256) sHist[i] = 0u;
  __syncthreads();

#pragma unroll
  for (int j = 0; j < CHUNK / 256; ++j) {
    const int e = base + j * 256 + tid;
    if (e < EE) atomicAdd(&sHist[dst[e] >> 7], 1u);
  }
  __syncthreads();

  {
    const unsigned s0 = sHist[4 * tid + 0];
    const unsigned s1 = sHist[4 * tid + 1];
    const unsigned s2 = sHist[4 * tid + 2];
    const unsigned s3 = sHist[4 * tid + 3];
    sPart[tid] = s0 + s1 + s2 + s3;
    __syncthreads();
    for (int off = 1; off < 256; off <<= 1) {
      unsigned v = 0u;
      if (tid >= off) v = sPart[tid - off];
      __syncthreads();
      if (tid >= off) sPart[tid] += v;
      __syncthreads();
    }
    const unsigned excl = (tid == 0) ? 0u : sPart[tid - 1];
    sScan[4 * tid + 0] = excl;
    sScan[4 * tid + 1] = excl + s0;
    sScan[4 * tid + 2] = excl + s0 + s1;
    sScan[4 * tid + 3] = excl + s0 + s1 + s2;
  }
  for (int i = tid; i < NB; i += 256) sCur[i] = 0u;
  __syncthreads();

#pragma unroll
  for (int j = 0; j < CHUNK / 256; ++j) {
    const int e = base + j * 256 + tid;
    if (e < EE) {
      const int s = src[e];
      const int d = dst[e];
      const int b = d >> 7;
      const unsigned p = sScan[b] + atomicAdd(&sCur[b], 1u);
      sPay[p] = ((d & 127) << 17) | s;
    }
  }
  __syncthreads();

  // coalesced payload dump (entries beyond this block's edge count are
  // garbage but never read — counts bound all consumers)
  {
    int4* g = (int4*)(ebuf + (size_t)bid * CHUNK);
    const int4* l = (const int4*)sPay;
#pragma unroll
    for (int i = tid; i < CHUNK / 4; i += 256) g[i] = l[i];
    for (int b = tid; b < NB; b += 256)
      tcnt[bid * 1024 + b] = (sScan[b] << 14) | sHist[b];   // scan<=8192 fits
  }
}

// ---------------------------------------------------------------------------
// GEMM body (R12 MFMA kernel, unchanged)
// ---------------------------------------------------------------------------
template <typename IN>
__device__ __forceinline__ void gemm_body(char* smem, int bid,
                                          const IN* __restrict__ X,
                                          const float* __restrict__ W,
                                          __half* __restrict__ H) {
  _Float16 (*sWT)[136] = (_Float16(*)[136])smem;   // 34816 B
  const int tid  = threadIdx.x;
  const int wave = tid >> 6;
  const int lane = tid & 63;
  const int quad = lane >> 4;
  const int m    = lane & 15;
  const int row0 = bid * 128;

  {
    const int n = tid & 127, g = tid >> 7;
#pragma unroll 4
    for (int j = 0; j < 32; ++j) {
      const int k = (g * 32 + j) * 2;
      union { _Float16 h[2]; uint32_t u; } p;
      p.h[0] = (_Float16)W[k * 128 + n];
      p.h[1] = (_Float16)W[(k + 1) * 128 + n];
      *(uint32_t*)&sWT[n][k] = p.u;
    }
  }
  __syncthreads();

  floatx4 acc[2][8];
#pragma unroll
  for (int rt = 0; rt < 2; ++rt)
#pragma unroll
    for (int ct = 0; ct < 8; ++ct) acc[rt][ct] = (floatx4){0.f, 0.f, 0.f, 0.f};

#pragma unroll
  for (int kk = 0; kk < 4; ++kk) {
    const int kb = kk * 32 + quad * 8;
    half8 a[2];
#pragma unroll
    for (int rt = 0; rt < 2; ++rt) {
      int gr = row0 + wave * 32 + rt * 16 + m;
      if (gr >= NN) gr = NN - 1;
      if constexpr (sizeof(IN) == 4) {
        const float4 lo = *(const float4*)(X + (size_t)gr * 128 + kb);
        const float4 hi = *(const float4*)(X + (size_t)gr * 128 + kb + 4);
        a[rt][0] = (_Float16)lo.x; a[rt][1] = (_Float16)lo.y;
        a[rt][2] = (_Float16)lo.z; a[rt][3] = (_Float16)lo.w;
        a[rt][4] = (_Float16)hi.x; a[rt][5] = (_Float16)hi.y;
        a[rt][6] = (_Float16)hi.z; a[rt][7] = (_Float16)hi.w;
      } else {
        a[rt] = *(const half8*)(X + (size_t)gr * 128 + kb);
      }
    }
#pragma unroll
    for (int ct = 0; ct < 8; ++ct) {
      const half8 b = *(const half8*)&sWT[ct * 16 + m][kb];
      acc[0][ct] = __builtin_amdgcn_mfma_f32_16x16x32_f16(a[0], b, acc[0][ct], 0, 0, 0);
      acc[1][ct] = __builtin_amdgcn_mfma_f32_16x16x32_f16(a[1], b, acc[1][ct], 0, 0, 0);
    }
  }

  __syncthreads();
#pragma unroll
  for (int rt = 0; rt < 2; ++rt)
#pragma unroll
    for (int reg = 0; reg < 4; ++reg) {
      const int row = wave * 32 + rt * 16 + quad * 4 + reg;
#pragma unroll
      for (int ct = 0; ct < 8; ++ct)
        sWT[row][ct * 16 + m] = (_Float16)acc[rt][ct][reg];
    }
  __syncthreads();
#pragma unroll
  for (int c = 0; c < 8; ++c) {
    const int chunk = tid + c * 256;
    const int row = chunk >> 4;
    const int seg = chunk & 15;
    const int gr = row0 + row;
    if (gr < NN)
      *(half8*)(H + (size_t)gr * 128 + seg * 8) =
          *(const half8*)&sWT[row][seg * 8];
  }
}

// ---------------------------------------------------------------------------
// Fused gemm1 || scatter (R13 structure; scatter blocks first)
// ---------------------------------------------------------------------------
__global__ __launch_bounds__(256) void k_g1s(const float* __restrict__ X,
                                             const float* __restrict__ W,
                                             __half* __restrict__ H,
                                             const int* __restrict__ src,
                                             const int* __restrict__ dst,
                                             int* __restrict__ ebuf,
                                             unsigned* __restrict__ tcnt) {
  __shared__ __align__(16) char smem[SMEM_BYTES];
  if (blockIdx.x < NBLK) {
    scatter_body(smem, blockIdx.x, src, dst, ebuf, tcnt);
  } else {
    gemm_body<float>(smem, blockIdx.x - NBLK, X, W, H);
  }
}

__global__ __launch_bounds__(256) void k_gemm2(const __half* __restrict__ X,
                                               const float* __restrict__ W,
                                               __half* __restrict__ H) {
  __shared__ __align__(16) char smem[34816];
  gemm_body<__half>(smem, blockIdx.x, X, W, H);
}

// ---------------------------------------------------------------------------
// Build R14: per bucket, walk the 196 block-runs (thread t owns runs
// x = t, t+256, ...; each run ~10.5 sequential loads), LDS ELL insert,
// coalesced dump + deg/dinv. No overflow pass (scatter is exact).
// ---------------------------------------------------------------------------
__global__ __launch_bounds__(256) void k_build(const unsigned* __restrict__ tcnt,
                                               const int* __restrict__ ebuf,
                                               int* __restrict__ ell,
                                               unsigned* __restrict__ deg,
                                               float* __restrict__ dinv) {
  __shared__ int      sEll[128 * ELLCAP];     // 32 KB
  __shared__ unsigned sFill[128];
  const int b   = blockIdx.x;
  const int tid = threadIdx.x;
  if (tid < 128) sFill[tid] = 0u;
  __syncthreads();

  for (int x = tid; x < NBLK; x += 256) {
    const unsigned t   = tcnt[x * 1024 + b];
    const unsigned off = t >> 14;
    const unsigned c   = t & 16383u;
    const int* p = ebuf + (size_t)x * CHUNK + off;
    for (unsigned i = 0; i < c; ++i) {
      const int pay = p[i];
      const int dl = (pay >> 17) & 127;
      const unsigned sl = atomicAdd(&sFill[dl], 1u);
      if (sl < ELLCAP) sEll[dl * ELLCAP + sl] = pay & 0x1FFFF;
    }
  }
  __syncthreads();

  const int node0 = b * 128;
  const int limRows = (NN - node0) < 128 ? (NN - node0) : 128;
  int4* g = (int4*)(ell + (size_t)node0 * ELLCAP);
  const int4* l = (const int4*)sEll;
  const int limV = limRows * (ELLCAP / 4);
  for (int i = tid; i < limV; i += 256) g[i] = l[i];
  if (tid < 128 && node0 + tid < NN) {
    const unsigned d = sFill[tid];
    deg[node0 + tid] = d;
    dinv[node0 + tid] = 1.0f / sqrtf((float)d + 1.0f);   // self-loop +1
  }
}

// ---------------------------------------------------------------------------
// Aggregation (unchanged R9/R11; near the per-XCD replication ceiling)
// ---------------------------------------------------------------------------
template <int LAYER>
__global__ __launch_bounds__(256) void k_agg(const __half* __restrict__ H,
                                             const int* __restrict__ ell,
                                             const unsigned* __restrict__ degc,
                                             const float* __restrict__ dinv,
                                             const float* __restrict__ bias,
                                             const float* __restrict__ Wl,
                                             const float* __restrict__ bl,
                                             void* __restrict__ outv) {
  const int tid  = threadIdx.x;
  const int lane = tid & 63;
  const int n    = blockIdx.x * 4 + (tid >> 6);

  const float di = dinv[n];
  const __half2* __restrict__ H2 = (const __half2*)H;

  const float2 hv = __half22float2(H2[(size_t)n * 64 + lane]);
  const float sw = di * di;
  float a0 = hv.x * sw, a1 = hv.y * sw;

  unsigned cnt = degc[n];
  if (cnt > ELLCAP) cnt = ELLCAP;
  const size_t s = (size_t)n * ELLCAP;

  {
    const int m = (int)cnt;
    int srcl = 0; float dl = 0.0f;
    if (lane < m) { srcl = ell[s + lane]; dl = dinv[srcl]; }
    int i = 0;
    for (; i + 4 <= m; i += 4) {
      const int s0 = __shfl(srcl, i + 0, 64);
      const int s1 = __shfl(srcl, i + 1, 64);
      const int s2 = __shfl(srcl, i + 2, 64);
      const int s3 = __shfl(srcl, i + 3, 64);
      const float w0 = __shfl(dl, i + 0, 64) * di;
      const float w1 = __shfl(dl, i + 1, 64) * di;
      const float w2 = __shfl(dl, i + 2, 64) * di;
      const float w3 = __shfl(dl, i + 3, 64) * di;
      const float2 g0 = __half22float2(H2[(size_t)s0 * 64 + lane]);
      const float2 g1 = __half22float2(H2[(size_t)s1 * 64 + lane]);
      const float2 g2 = __half22float2(H2[(size_t)s2 * 64 + lane]);
      const float2 g3 = __half22float2(H2[(size_t)s3 * 64 + lane]);
      a0 = fmaf(w0, g0.x, a0); a1 = fmaf(w0, g0.y, a1);
      a0 = fmaf(w1, g1.x, a0); a1 = fmaf(w1, g1.y, a1);
      a0 = fmaf(w2, g2.x, a0); a1 = fmaf(w2, g2.y, a1);
      a0 = fmaf(w3, g3.x, a0); a1 = fmaf(w3, g3.y, a1);
    }
    for (; i < m; i++) {
      const int src   = __shfl(srcl, i, 64);
      const float wgt = __shfl(dl, i, 64) * di;
      const float2 g  = __half22float2(H2[(size_t)src * 64 + lane]);
      a0 = fmaf(wgt, g.x, a0); a1 = fmaf(wgt, g.y, a1);
    }
  }

  const float2 b = ((const float2*)bias)[lane];
  float v0 = a0 + b.x, v1 = a1 + b.y;
  v0 = v0 >= 0.f ? v0 : 0.01f * v0;
  v1 = v1 >= 0.f ? v1 : 0.01f * v1;

  const uint32_t k0 = (LAYER == 1) ? DK1.x0 : DK2.x0;
  const uint32_t k1 = (LAYER == 1) ? DK1.x1 : DK2.x1;
  const uint32_t mb = (uint32_t)n * 128u + (uint32_t)lane * 2u;
  v0 *= drop_scale(k0, k1, mb + 0u);
  v1 *= drop_scale(k0, k1, mb + 1u);

  if constexpr (LAYER == 1) {
    __half2* out = (__half2*)outv;
    out[(size_t)n * 64 + lane] = __floats2half2_rn(v0, v1);
  } else {
    float* out = (float*)outv;
    const float2 wl = ((const float2*)Wl)[lane];
    float p = v0 * wl.x + v1 * wl.y;
#pragma unroll
    for (int d = 32; d > 0; d >>= 1) p += __shfl_down(p, d, 64);
    if (lane == 0) out[n] = p + bl[0];
  }
}

// ---------------------------------------------------------------------------
extern "C" void kernel_launch(void* const* d_in, const int* in_sizes, int n_in,
                              void* d_out, int out_size, void* d_ws, size_t ws_size,
                              hipStream_t stream) {
  const float* x  = (const float*)d_in[0];
  const int*   ei = (const int*)d_in[1];
  const float* W1 = (const float*)d_in[2];
  const float* b1 = (const float*)d_in[3];
  const float* W2 = (const float*)d_in[4];
  const float* b2 = (const float*)d_in[5];
  const float* Wl = (const float*)d_in[6];
  const float* bl = (const float*)d_in[7];
  float* out = (float*)d_out;

  // workspace (~78 MB): ebuf(6.4 MB)+tcnt(0.8 MB) ALIAS bufB (dead til agg1)
  unsigned* deg  = (unsigned*)d_ws;                        // NN u32
  float*    dinv = (float*)(deg + NN);                     // NN f32
  int*      ell  = (int*)(dinv + NN);                      // NN*64 (25.6 MB)
  __half*   bufA = (__half*)(ell + (size_t)NN * ELLCAP);   // NN*128 fp16
  __half*   bufB = bufA + (size_t)NN * FD;                 // NN*128 fp16 (y1)
  int*      ebuf = (int*)bufB;                             // NBLK*CHUNK ints
  unsigned* tcnt = (unsigned*)(ebuf + (size_t)NBLK * CHUNK); // NBLK*1024 u32

  const int* srcI = ei;
  const int* dstI = ei + EE;

  const int gemmGrid = (NN + 127) / 128;   // 782
  k_g1s<<<NBLK + gemmGrid, 256, 0, stream>>>(x, W1, bufA, srcI, dstI,
                                             ebuf, tcnt);
  k_build<<<NB, 256, 0, stream>>>(tcnt, ebuf, ell, deg, dinv);
  k_agg<1><<<NN / 4, 256, 0, stream>>>(bufA, ell, deg, dinv,
                                       b1, nullptr, nullptr, bufB);  // y1 fp16
  k_gemm2<<<gemmGrid, 256, 0, stream>>>(bufB, W2, bufA);             // h2 fp16
  k_agg<2><<<NN / 4, 256, 0, stream>>>(bufA, ell, deg, dinv,
                                       b2, Wl, bl, out);             // out
}